// Round 1
// 409.880 us; speedup vs baseline: 1.2365x; 1.2365x over previous
//
#include <hip/hip_runtime.h>

#define T_LEN 1024
#define P_DIM 32
#define HOME_IDX 0

// One wave (64 threads) per batch b. Lane layout: p = lane&31 (output state),
// h = lane>>5 (which half of the 32 predecessors q this lane scans).
//
// Latency-bound regime: 1 wave/CU, 1023 serially-dependent steps. This version
// minimizes the per-step dependence chain:
//  * delta1[q] broadcast via 16 ds_bpermute (register->register, no LDS round
//    trip, no barriers): one DS latency on the chain instead of write+wait+read.
//  * value/index split: the recurrence needs only VALUE v1 = max_q(...), done
//    with an fmax/v_max3 tree (depth 3). The argmax index (needed only for the
//    psi backtrack byte) is recovered OFF the critical path by an equality scan
//    c[j]==v1 (exact: fmax returns one of its inputs; +-0 is compare-equal so
//    first-index semantics match jnp.argmax; no NaNs - all values finite).
//  * prefetch ring depth 4 in static register slots (fully unrolled x4 loop);
//    Ut = u + bias and its lane-0 broadcast (wave-uniform v=0 chain) are
//    prepared one step early so shuffle/load latency is hidden.
//  * psi byte: cond = use1 || is_home; byte = cond ? (a1|32) : 0
//    (p1 = cond ? a1 : 0, vv1 = cond; uses a0 == 0 exactly).
//
// Exactness notes (carried over):
//  * NEG = finfo(f32).min/4; ulp(NEG) ~ 1e31 >> |A|<=0.01, so NEG + A == NEG;
//    the v=0 slice is NEG except q=HOME -> v0[p] = delta0h + A[0][p], a0 = 0.
//  * use1 = (v1 > v0) strict, matching the reference.
//  * delta0h update order preserved: (delta0h + A00) + (u[t,0] + bias0).

__launch_bounds__(64, 1)
__global__ void crf_viterbi_kernel(const float* __restrict__ U,
                                   const float* __restrict__ A,
                                   const float* __restrict__ bias,
                                   int* __restrict__ out)
{
    __shared__ unsigned char spsi[(T_LEN - 1) * P_DIM];   // 32736 bytes

    const int b    = blockIdx.x;
    const int lane = threadIdx.x;
    const int p    = lane & 31;
    const int h    = lane >> 5;
    const float NEG = -(3.4028234663852886e38f / 4.0f);

    // A fragment: A[q][p] for q = 16*h + j
    float Areg[16];
#pragma unroll
    for (int j = 0; j < 16; ++j)
        Areg[j] = A[(16 * h + j) * P_DIM + p];
    const float A0p    = A[p];        // A[HOME][p]
    const float A00    = A[0];        // A[HOME][HOME]
    const float bias_p = bias[p];
    const float bias0  = bias[0];
    const int   qb     = h << 6;      // bpermute byte base: lane (16h+j) -> (16h+j)*4
    const bool  is_home = (p == HOME_IDX);

    const float* __restrict__ Ub = U + (size_t)b * T_LEN * P_DIM;

    // t = 0 init
    float u0      = Ub[p] + bias_p;
    float delta1  = is_home ? NEG : u0;      // v=1 slice, per-lane p
    float delta0h = Ub[HOME_IDX] + bias0;    // v=0 slice at HOME (wave-uniform)

    // Prefetch ring, depth 4. Row t lives in slot (t-1)&3.
    float L0 = Ub[1 * P_DIM + p];
    float L1 = Ub[2 * P_DIM + p];
    float L2 = Ub[3 * P_DIM + p];
    float L3 = Ub[4 * P_DIM + p];

    // Prepared-one-early pipeline: Ut_n / u0_n are for the NEXT step.
    float Ut_n = L0 + bias_p;          // for t = 1
    float u0_n = __shfl(Ut_n, 0);      // u[t,0] + bias0, broadcast

// STEP(t, Lc, Lr):
//   consume (Ut, u0c) prepared last step; prepare next from Lc = L[t&3];
//   reload Lr = L[(t-1)&3] with row t+4 (clamped);
//   run one Viterbi step; store psi byte; update delta1/delta0h.
#define STEP(t, Lc, Lr) do {                                                   \
    const float Ut  = Ut_n;                                                    \
    const float u0c = u0_n;                                                    \
    Ut_n = (Lc) + bias_p;                                                      \
    u0_n = __shfl(Ut_n, 0);                                                    \
    {                                                                          \
        int tn = (t) + 4;                                                      \
        if (tn > T_LEN - 1) tn = T_LEN - 1;                                    \
        (Lr) = Ub[(size_t)tn * P_DIM + p];                                     \
    }                                                                          \
    const int dsrc = __float_as_int(delta1);                                   \
    float c[16];                                                               \
    _Pragma("unroll")                                                          \
    for (int j = 0; j < 16; ++j)                                               \
        c[j] = __int_as_float(__builtin_amdgcn_ds_bpermute(qb + 4 * j, dsrc))  \
               + Areg[j];                                                      \
    /* value-only max tree (v_max3-friendly, depth 3) */                       \
    const float g0 = fmaxf(fmaxf(c[0],  c[1]),  c[2]);                         \
    const float g1 = fmaxf(fmaxf(c[3],  c[4]),  c[5]);                         \
    const float g2 = fmaxf(fmaxf(c[6],  c[7]),  c[8]);                         \
    const float g3 = fmaxf(fmaxf(c[9],  c[10]), c[11]);                        \
    const float g4 = fmaxf(fmaxf(c[12], c[13]), c[14]);                        \
    const float h0 = fmaxf(fmaxf(g0, g1), g2);                                 \
    const float h1 = fmaxf(fmaxf(g3, g4), c[15]);                              \
    const float bv = fmaxf(h0, h1);                                            \
    const float ovv = __shfl_xor(bv, 32);                                      \
    const float v1  = fmaxf(bv, ovv);                                          \
    const float v0  = delta0h + A0p;                                           \
    const bool  use1 = (v1 > v0);              /* strict, as reference */      \
    const bool  cond = use1 || is_home;                                        \
    const float sel  = cond ? v1 : v0;                                         \
    const float dn1  = sel + Ut;                                               \
    delta0h = (delta0h + A00) + u0c;                                           \
    /* index recovery (off critical path): first q with c == v1 */             \
    int ia = 99;                                                               \
    _Pragma("unroll")                                                          \
    for (int j = 15; j >= 0; --j)                                              \
        if (c[j] == v1) ia = (qb >> 2) + j;                                    \
    const int oia = __shfl_xor(ia, 32);                                        \
    const int a1  = (ia < oia) ? ia : oia;                                     \
    const int bt  = cond ? (a1 | 32) : 0;                                      \
    spsi[(size_t)((t) - 1) * P_DIM + p] = (unsigned char)bt;                   \
    delta1 = dn1;                                                              \
} while (0)

    // Prologue: t = 1..3, then quads t = 4..1023 (1020 = 4*255 steps).
    STEP(1, L1, L0);
    STEP(2, L2, L1);
    STEP(3, L3, L2);
    for (int t = 4; t <= T_LEN - 4; t += 4) {
        STEP(t + 0, L0, L3);
        STEP(t + 1, L1, L0);
        STEP(t + 2, L2, L1);
        STEP(t + 3, L3, L2);
    }
#undef STEP

    __syncthreads();   // drain psi LDS writes before backtrack reads

    // last_p = argmax_p delta_T[:,1], first index wins (lexicographic butterfly;
    // lanes 32..63 are duplicates of p = lane-32, idx tie-break handles them).
    float mv = delta1;
    int   mi = p;
#pragma unroll
    for (int m = 16; m >= 1; m >>= 1) {
        float ov = __shfl_xor(mv, m);
        int   oi = __shfl_xor(mi, m);
        bool take = (ov > mv) || ((ov == mv) && (oi < mi));
        mv = take ? ov : mv;
        mi = take ? oi : mi;
    }
    const int last_p = mi;

    int* __restrict__ outb = out + (size_t)b * T_LEN;
    if (lane == 0) {
        outb[T_LEN - 1] = last_p;
        int y = last_p;
        int i = T_LEN - 2;
        for (; i >= 0; --i) {
            const int bt = spsi[i * P_DIM + y];
            const int py = bt & 31;
            outb[i] = py;
            y = py;
            if (!(bt & 32)) break;   // v hit 0: rest of the path is all HOME=0
        }
        for (--i; i >= 0; --i) outb[i] = 0;
    }
}

extern "C" void kernel_launch(void* const* d_in, const int* in_sizes, int n_in,
                              void* d_out, int out_size, void* d_ws, size_t ws_size,
                              hipStream_t stream) {
    const float* U    = (const float*)d_in[0];   // (B, T, P) f32
    const float* A    = (const float*)d_in[1];   // (P, P)    f32
    const float* bias = (const float*)d_in[2];   // (P,)      f32
    int* out = (int*)d_out;                      // (B, T)    int32

    const int B = in_sizes[0] / (T_LEN * P_DIM);
    crf_viterbi_kernel<<<B, 64, 0, stream>>>(U, A, bias, out);
}

// Round 4
// 338.487 us; speedup vs baseline: 1.4973x; 1.2109x over previous
//
#include <hip/hip_runtime.h>

#define T_LEN 1024
#define P_DIM 32
#define HOME_IDX 0
#define NCHUNK 32
#define CHUNK 32

// A/B-isolation round: forward pass is the harness-PROVEN round-1 kernel
// (ds_bpermute broadcast, value/index split, depth-4 prefetch ring),
// transplanted verbatim under a tid<64 guard. The ONLY new subsystem is the
// chunked parallel backtrack (phases 1-3 below) using the other 15 waves.
//
// Forward-path exactness notes (harness-verified at 348 us):
//  * NEG = finfo(f32).min/4; ulp(NEG) >> |A|<=0.01, so NEG + A == NEG; the
//    v=0 slice is NEG except q=HOME -> v0[p] = delta0h + A[0][p], a0 = 0.
//  * use1 = (v1 > v0) strict, matching the reference.
//  * argmax recovered off-path by equality scan c[j]==v1 (fmax returns one of
//    its inputs bit-exactly; +-0 compare equal; inputs NaN-free), descending-j
//    scan + cross-half min-index => first-index semantics.
//  * delta0h update order preserved: (delta0h + A00) + (u[t,0] + bias0).
//
// Backtrack: 1023 backsteps in 32 chunks of <=32. Phase 1: 1024 threads build
// per-chunk (y,v)-maps for all 32 v=1 entry states (32 dependent LDS reads
// instead of 1023). Phase 2: one thread composes maps from (last_p,1); v=0 is
// absorbing at (0,0). Phase 3: 32 lanes re-walk their chunk from its true
// entry emitting out[i]. Per-backstep rule identical to the proven serial one:
// if v: (y,v) = (byte&31, (byte>>5)&1) else (0,0); out[i] = new y.

__launch_bounds__(1024, 1)
__global__ void crf_viterbi_kernel(const float* __restrict__ U,
                                   const float* __restrict__ A,
                                   const float* __restrict__ bias,
                                   int* __restrict__ out)
{
    __shared__ unsigned char spsi[(T_LEN - 1) * P_DIM];   // 32736 B
    __shared__ unsigned char Mmap[NCHUNK * P_DIM];        // chunk maps
    __shared__ unsigned char ent[NCHUNK];                 // chunk entry states
    __shared__ int last_p_sh;

    const int tid = threadIdx.x;
    const int b   = blockIdx.x;
    int* __restrict__ outb = out + (size_t)b * T_LEN;

    if (tid < 64) {
        const int lane = tid;
        const int p    = lane & 31;
        const int h    = lane >> 5;
        const float NEG = -(3.4028234663852886e38f / 4.0f);

        // A fragment: A[q][p] for q = 16*h + j
        float Areg[16];
#pragma unroll
        for (int j = 0; j < 16; ++j)
            Areg[j] = A[(16 * h + j) * P_DIM + p];
        const float A0p    = A[p];        // A[HOME][p]
        const float A00    = A[0];        // A[HOME][HOME]
        const float bias_p = bias[p];
        const float bias0  = bias[0];
        const int   qb     = h << 6;      // bpermute byte base
        const bool  is_home = (p == HOME_IDX);

        const float* __restrict__ Ub = U + (size_t)b * T_LEN * P_DIM;

        // t = 0 init
        const float u00 = Ub[p] + bias_p;
        float delta1  = is_home ? NEG : u00;     // v=1 slice, per-lane p
        float delta0h = Ub[HOME_IDX] + bias0;    // v=0 slice at HOME (uniform)

        // Prefetch ring, depth 4. Row t lives in slot (t-1)&3.
        float L0 = Ub[1 * P_DIM + p];
        float L1 = Ub[2 * P_DIM + p];
        float L2 = Ub[3 * P_DIM + p];
        float L3 = Ub[4 * P_DIM + p];

        float Ut_n = L0 + bias_p;          // for t = 1
        float u0_n = __shfl(Ut_n, 0);      // u[t,0] + bias0, broadcast

#define STEP(t, Lc, Lr) do {                                                   \
    const float Ut  = Ut_n;                                                    \
    const float u0c = u0_n;                                                    \
    Ut_n = (Lc) + bias_p;                                                      \
    u0_n = __shfl(Ut_n, 0);                                                    \
    { int tn = (t) + 4; if (tn > T_LEN - 1) tn = T_LEN - 1;                    \
      (Lr) = Ub[(size_t)tn * P_DIM + p]; }                                     \
    const int dsrc = __float_as_int(delta1);                                   \
    float c[16];                                                               \
    _Pragma("unroll")                                                          \
    for (int j = 0; j < 16; ++j)                                               \
        c[j] = __int_as_float(__builtin_amdgcn_ds_bpermute(qb + 4 * j, dsrc))  \
               + Areg[j];                                                      \
    /* value-only max tree (v_max3-friendly, depth 3) */                       \
    const float g0 = fmaxf(fmaxf(c[0],  c[1]),  c[2]);                         \
    const float g1 = fmaxf(fmaxf(c[3],  c[4]),  c[5]);                         \
    const float g2 = fmaxf(fmaxf(c[6],  c[7]),  c[8]);                         \
    const float g3 = fmaxf(fmaxf(c[9],  c[10]), c[11]);                        \
    const float g4 = fmaxf(fmaxf(c[12], c[13]), c[14]);                        \
    const float h0 = fmaxf(fmaxf(g0, g1), g2);                                 \
    const float h1 = fmaxf(fmaxf(g3, g4), c[15]);                              \
    const float bv = fmaxf(h0, h1);                                            \
    const float ovv = __shfl_xor(bv, 32);                                      \
    const float v1  = fmaxf(bv, ovv);                                          \
    const float v0  = delta0h + A0p;                                           \
    const bool  use1 = (v1 > v0);              /* strict, as reference */      \
    const bool  cond = use1 || is_home;                                        \
    const float sel  = cond ? v1 : v0;                                         \
    const float dn1  = sel + Ut;                                               \
    delta0h = (delta0h + A00) + u0c;                                           \
    /* index recovery (off critical path): first q with c == v1 */             \
    int ia = 99;                                                               \
    _Pragma("unroll")                                                          \
    for (int j = 15; j >= 0; --j)                                              \
        if (c[j] == v1) ia = (qb >> 2) + j;                                    \
    const int oia = __shfl_xor(ia, 32);                                        \
    const int a1  = (ia < oia) ? ia : oia;                                     \
    const int bt  = cond ? (a1 | 32) : 0;                                      \
    spsi[(size_t)((t) - 1) * P_DIM + p] = (unsigned char)bt;                   \
    delta1 = dn1;                                                              \
} while (0)

        STEP(1, L1, L0);
        STEP(2, L2, L1);
        STEP(3, L3, L2);
        for (int t = 4; t <= T_LEN - 4; t += 4) {
            STEP(t + 0, L0, L3);
            STEP(t + 1, L1, L0);
            STEP(t + 2, L2, L1);
            STEP(t + 3, L3, L2);
        }
#undef STEP

        // last_p = argmax_p delta_T[:,1], first index wins (lexicographic
        // butterfly; lanes 32..63 duplicate p = lane-32, idx tie-break wins).
        float mv = delta1;
        int   mi = p;
#pragma unroll
        for (int m = 16; m >= 1; m >>= 1) {
            float ov = __shfl_xor(mv, m);
            int   oi = __shfl_xor(mi, m);
            bool take = (ov > mv) || ((ov == mv) && (oi < mi));
            mv = take ? ov : mv;
            mi = take ? oi : mi;
        }
        if (lane == 0) {
            outb[T_LEN - 1] = mi;
            last_p_sh = mi;
        }
    }

    __syncthreads();   // psi + last_p visible to all 16 waves

    // Phase 1: per-chunk maps. Chunk c covers backsteps i in
    // [32c, min(32c+32, 1023)). Thread (c = tid>>5, pp = tid&31) walks from
    // hypothetical entry (pp, v=1).
    {
        const int c  = tid >> 5;
        const int pp = tid & 31;
        const int i_hi = min((c + 1) * CHUNK, T_LEN - 1);
        const int i_lo = c * CHUNK;
        int y = pp, v = 1;
        for (int i = i_hi - 1; i >= i_lo; --i) {
            const int bt = spsi[i * P_DIM + y];
            const int py = v ? (bt & 31) : 0;
            const int nv = v ? ((bt >> 5) & 1) : 0;
            y = py; v = nv;
        }
        Mmap[c * P_DIM + pp] = (unsigned char)(y | (v << 5));
    }
    __syncthreads();

    // Phase 2: compose maps from the top to get each chunk's true entry state.
    if (tid == 0) {
        int y = last_p_sh, v = 1;
        for (int c = NCHUNK - 1; c >= 0; --c) {
            ent[c] = (unsigned char)(y | (v << 5));
            if (v) {
                const int m = Mmap[c * P_DIM + y];
                y = m & 31;
                v = (m >> 5) & 1;
            } else {
                y = 0; v = 0;
            }
        }
    }
    __syncthreads();

    // Phase 3: 32 lanes re-walk their chunk from the true entry, emitting out.
    if (tid < NCHUNK) {
        const int c = tid;
        const int i_hi = min((c + 1) * CHUNK, T_LEN - 1);
        const int i_lo = c * CHUNK;
        const int e = ent[c];
        int y = e & 31;
        int v = (e >> 5) & 1;
        for (int i = i_hi - 1; i >= i_lo; --i) {
            const int bt = spsi[i * P_DIM + y];
            const int py = v ? (bt & 31) : 0;
            const int nv = v ? ((bt >> 5) & 1) : 0;
            outb[i] = py;
            y = py; v = nv;
        }
    }
}

extern "C" void kernel_launch(void* const* d_in, const int* in_sizes, int n_in,
                              void* d_out, int out_size, void* d_ws, size_t ws_size,
                              hipStream_t stream) {
    const float* U    = (const float*)d_in[0];   // (B, T, P) f32
    const float* A    = (const float*)d_in[1];   // (P, P)    f32
    const float* bias = (const float*)d_in[2];   // (P,)      f32
    int* out = (int*)d_out;                      // (B, T)    int32

    const int B = in_sizes[0] / (T_LEN * P_DIM);
    crf_viterbi_kernel<<<B, 1024, 0, stream>>>(U, A, bias, out);
}